// Round 14
// baseline (79.664 us; speedup 1.0000x reference)
//
#include <hip/hip_runtime.h>
#include <math.h>

#define DD 128
#define NSPLIT 24
#define NBINS 512
#define SHIFT 10.0f
#define L2E_T 14.4269504089f   // 10 * log2(e)

typedef _Float16 f16x8 __attribute__((ext_vector_type(8)));
typedef _Float16 f16x2 __attribute__((ext_vector_type(2)));
typedef float f32x4 __attribute__((ext_vector_type(4)));

// guard-free 2^x: args are in [-29, 0], no denorm/overflow concerns
__device__ __forceinline__ float ex2(float x) {
#if __has_builtin(__builtin_amdgcn_exp2f)
    return __builtin_amdgcn_exp2f(x);
#else
    return exp2f(x);
#endif
}

// ---- tiny zero: hist (512 ints) + d_out; 1 block, ~1us ----
__global__ __launch_bounds__(256)
void zero_kernel(int* __restrict__ hist, float* __restrict__ out)
{
    hist[threadIdx.x] = 0;
    hist[256 + threadIdx.x] = 0;
    if (threadIdx.x == 0) out[0] = 0.f;
}

// ---- normalize rows -> f16, labels, histogram ----
__global__ __launch_bounds__(256)
void norm_kernel(const float* __restrict__ f, const int* __restrict__ labels,
                 _Float16* __restrict__ fh, int* __restrict__ labm,
                 int* __restrict__ hist, int M, int nrep)
{
    int gw = (blockIdx.x * 256 + threadIdx.x) >> 6;   // one wave per row
    int lane = threadIdx.x & 63;
    if (gw >= M) return;
    float2 v = *reinterpret_cast<const float2*>(&f[(size_t)gw * DD + lane * 2]);
    float ss = v.x * v.x + v.y * v.y;
    #pragma unroll
    for (int m = 1; m < 64; m <<= 1) ss += __shfl_xor(ss, m);
    float inv = 1.0f / fmaxf(sqrtf(ss), 1e-12f);
    f16x2 h; h[0] = (_Float16)(v.x * inv); h[1] = (_Float16)(v.y * inv);
    *reinterpret_cast<f16x2*>(&fh[(size_t)gw * DD + lane * 2]) = h;
    if (lane == 0) {
        int lb = labels[gw / nrep];
        labm[gw] = lb;
        if ((gw % nrep) == 0) atomicAdd(&hist[lb], nrep);  // one atomic per sample
    }
}

// ---- main: barrier-free f16 MFMA stream; TRIPLE-buffered j-subtiles ----
// R12 schedule (4 waves/block, 64 i-rows register-resident, (256,3), raw
// v_exp_f32, grid 32x24 = 768 = 3 blocks/CU) with prefetch distance widened
// from ~1 to 3 half-subtiles (af0/af1/af2 rotation, unroll-3): each buffer's
// loads get ~1200 cyc of issue-cover before their consuming MFMA's vmcnt
// wait (R12's ~300 was marginal vs L2 latency; counters showed 75% stall).
// Indices past the range end are clamped to the global last subtile
// (in-bounds redundant loads). Self-pair included; final subtracts exactly.
__global__ __launch_bounds__(256, 3)
void supcon_main(const _Float16* __restrict__ fh, const int* __restrict__ labm,
                 float* __restrict__ Epart, float* __restrict__ Ppart,
                 int M, int nsub_total)
{
    const int lane = threadIdx.x & 63;
    const int w = threadIdx.x >> 6;
    const int ibase = blockIdx.x * 256 + w * 64;
    const int rowsel = lane & 15;
    const int grp = lane >> 4;
    const int ksel = grp * 8;      // f16 k-offset within a 32-wide K step

    // register-resident Fi fragments: 4 subtiles x 4 K-steps = 64 regs
    f16x8 bfr[4][4];
    #pragma unroll
    for (int t = 0; t < 4; ++t)
        #pragma unroll
        for (int kk = 0; kk < 4; ++kk)
            bfr[t][kk] = *reinterpret_cast<const f16x8*>(
                &fh[(size_t)(ibase + t * 16 + rowsel) * DD + kk * 32 + ksel]);

    int li[4];
    #pragma unroll
    for (int t = 0; t < 4; ++t) li[t] = labm[ibase + t * 16 + rowsel];

    float esum[4] = {0.f, 0.f, 0.f, 0.f};
    float psum[4] = {0.f, 0.f, 0.f, 0.f};

    // uneven subtile range for this j-split
    const int base = nsub_total / NSPLIT, rem = nsub_total % NSPLIT;
    const int by = blockIdx.y;
    const int s0 = by * base + (by < rem ? by : rem);
    const int send = s0 + base + (by < rem ? 1 : 0);
    const int smax = nsub_total - 1;

    const _Float16* aptr = fh + (size_t)rowsel * DD + ksel;  // + s*16*DD per subtile
    const int* lptr = labm + grp * 4;

#define LOADT(A, L, s) { \
    _Pragma("unroll") for (int kk = 0; kk < 4; ++kk) \
        A[kk] = *reinterpret_cast<const f16x8*>(aptr + (size_t)(s) * 16 * DD + kk * 32); \
    L = *reinterpret_cast<const int4*>(lptr + (s) * 16); }

#define MFMA16(A, c0, c1, c2, c3) { \
    _Pragma("unroll") for (int kk = 0; kk < 4; ++kk) { \
        c0 = __builtin_amdgcn_mfma_f32_16x16x32_f16(A[kk], bfr[0][kk], c0, 0, 0, 0); \
        c1 = __builtin_amdgcn_mfma_f32_16x16x32_f16(A[kk], bfr[1][kk], c1, 0, 0, 0); \
        c2 = __builtin_amdgcn_mfma_f32_16x16x32_f16(A[kk], bfr[2][kk], c2, 0, 0, 0); \
        c3 = __builtin_amdgcn_mfma_f32_16x16x32_f16(A[kk], bfr[3][kk], c3, 0, 0, 0); } }

#define EPI1(t, cc, L) { \
    esum[t] += (ex2(__builtin_fmaf(cc[0], L2E_T, -L2E_T)) \
              + ex2(__builtin_fmaf(cc[1], L2E_T, -L2E_T))) \
             + (ex2(__builtin_fmaf(cc[2], L2E_T, -L2E_T)) \
              + ex2(__builtin_fmaf(cc[3], L2E_T, -L2E_T))); \
    float p0 = (L.x == li[t]) ? cc[0] : 0.f; \
    float p1 = (L.y == li[t]) ? cc[1] : 0.f; \
    float p2 = (L.z == li[t]) ? cc[2] : 0.f; \
    float p3 = (L.w == li[t]) ? cc[3] : 0.f; \
    psum[t] += (p0 + p1) + (p2 + p3); }

#define EPI4(c0, c1, c2, c3, L) { \
    EPI1(0, c0, L); EPI1(1, c1, L); EPI1(2, c2, L); EPI1(3, c3, L); }

// one pipeline phase: compute AF's subtile, reload AF with subtile snext
// (clamped in-bounds), epilogue with AF's old labels, rotate labels.
#define PHASE(AF, LJ, snext) { \
    f32x4 c0 = {0,0,0,0}, c1 = {0,0,0,0}, c2 = {0,0,0,0}, c3 = {0,0,0,0}; \
    MFMA16(AF, c0, c1, c2, c3); \
    int sc = (snext); if (sc > smax) sc = smax; \
    int4 ljn; LOADT(AF, ljn, sc); \
    EPI4(c0, c1, c2, c3, LJ); \
    LJ = ljn; }

    f16x8 af0[4], af1[4], af2[4];
    int4 lj0, lj1, lj2;
    LOADT(af0, lj0, s0);
    LOADT(af1, lj1, s0 + 1);     // ranges are >= 21 subtiles: in-bounds
    LOADT(af2, lj2, s0 + 2);

    int s = s0;
    for (; s + 2 < send; s += 3) {
        PHASE(af0, lj0, s + 3);
        PHASE(af1, lj1, s + 4);
        PHASE(af2, lj2, s + 5);
    }
    // tail (0-2 subtiles): af0 holds s, af1 holds s+1 from the rotation
    if (s < send) {
        f32x4 c0 = {0,0,0,0}, c1 = {0,0,0,0}, c2 = {0,0,0,0}, c3 = {0,0,0,0};
        MFMA16(af0, c0, c1, c2, c3);
        EPI4(c0, c1, c2, c3, lj0);
    }
    if (s + 1 < send) {
        f32x4 c0 = {0,0,0,0}, c1 = {0,0,0,0}, c2 = {0,0,0,0}, c3 = {0,0,0,0};
        MFMA16(af1, c0, c1, c2, c3);
        EPI4(c0, c1, c2, c3, lj1);
    }
#undef LOADT
#undef MFMA16
#undef EPI1
#undef EPI4
#undef PHASE

    // fold lane groups (bits 4,5 = different j rows of the same i)
    #pragma unroll
    for (int t = 0; t < 4; ++t) {
        float e = esum[t], p = psum[t];
        e += __shfl_xor(e, 16); e += __shfl_xor(e, 32);
        p += __shfl_xor(p, 16); p += __shfl_xor(p, 32);
        if (lane < 16) {
            size_t o = (size_t)by * M + ibase + t * 16 + lane;
            Epart[o] = e;
            Ppart[o] = p;
        }
    }
}

// ---- per-row loss term: one thread per row, coalesced partial reads,
// block-reduce, one atomic per block (R13: fixed the 2048-contended-atomic
// serialization, -27us) ----
__global__ __launch_bounds__(256)
void final_fused(const _Float16* __restrict__ fh, const float* __restrict__ Epart,
                 const float* __restrict__ Ppart, const int* __restrict__ labm,
                 const int* __restrict__ hist, float* __restrict__ out, int M)
{
    __shared__ float red[4];
    const int i = blockIdx.x * 256 + threadIdx.x;   // one row per thread
    // self-dot a_ii from f16 row (matches the MFMA diagonal term)
    float aii = 0.f;
    const f16x8* fr = reinterpret_cast<const f16x8*>(&fh[(size_t)i * DD]);
    #pragma unroll
    for (int k = 0; k < 16; ++k) {
        f16x8 hv = fr[k];
        #pragma unroll
        for (int e = 0; e < 8; ++e) {
            float x = (float)hv[e];
            aii = __builtin_fmaf(x, x, aii);
        }
    }
    // partial sums: coalesced (consecutive i across lanes, same k)
    float E = 0.f, P = 0.f;
    #pragma unroll
    for (int k = 0; k < NSPLIT; ++k) {
        E += Epart[(size_t)k * M + i];
        P += Ppart[(size_t)k * M + i];
    }
    int lb = labm[i];
    float cnt = (float)(hist[lb] - 1);
    E -= ex2(__builtin_fmaf(aii, L2E_T, -L2E_T));   // drop self exp
    float term = (SHIFT + logf(E)) - SHIFT * (P - aii) / cnt;

    #pragma unroll
    for (int m = 1; m < 64; m <<= 1) term += __shfl_xor(term, m);
    int lane = threadIdx.x & 63, wv = threadIdx.x >> 6;
    if (lane == 0) red[wv] = term;
    __syncthreads();
    if (threadIdx.x == 0)
        atomicAdd(out, (red[0] + red[1] + red[2] + red[3]) / (float)M);
}

extern "C" void kernel_launch(void* const* d_in, const int* in_sizes, int n_in,
                              void* d_out, int out_size, void* d_ws, size_t ws_size,
                              hipStream_t stream)
{
    const float* feats = (const float*)d_in[0];
    const int* labels = (const int*)d_in[1];
    const int Bn = in_sizes[1];
    const int M = in_sizes[0] / DD;    // 8192
    const int nrep = M / Bn;           // 2

    char* ws = (char*)d_ws;
    _Float16* fh = (_Float16*)ws;
    size_t off = (size_t)M * DD * sizeof(_Float16);
    int* labm = (int*)(ws + off); off += (size_t)M * sizeof(int);
    int* hist = (int*)(ws + off); off += (size_t)NBINS * sizeof(int);
    off = (off + 255) & ~(size_t)255;
    float* Epart = (float*)(ws + off); off += (size_t)NSPLIT * M * sizeof(float);
    float* Ppart = (float*)(ws + off); off += (size_t)NSPLIT * M * sizeof(float);

    zero_kernel<<<1, 256, 0, stream>>>(hist, (float*)d_out);

    norm_kernel<<<M / 4, 256, 0, stream>>>(feats, labels, fh, labm, hist, M, nrep);

    const int nsub_total = M / 16;     // 512 j-subtiles split unevenly over 24
    dim3 grid(M / 256, NSPLIT);        // 32 x 24 = 768 blocks (3/CU, 1 round)
    supcon_main<<<grid, 256, 0, stream>>>(fh, labm, Epart, Ppart, M, nsub_total);

    final_fused<<<M / 256, 256, 0, stream>>>(fh, Epart, Ppart, labm, hist,
                                             (float*)d_out, M);
}